// Round 9
// baseline (313.491 us; speedup 1.0000x reference)
//
#include <hip/hip_runtime.h>

#define CIN   256
#define COUT  256
#define HH    56
#define WW    56
#define BATCH 32
#define KTOT  2304           // CIN * 9, ordered (kh,kw,ci)
#define HP    58
#define WP    58
#define NPIX  (BATCH*HH*WW)  // 100352
#define HWSZ  (HH*WW)        // 3136
#define BN    224            // pixel tile -> 448 blocks
#define NBLK  (NPIX/BN)      // 448

typedef __bf16 bf16x8 __attribute__((ext_vector_type(8)));
typedef float  f32x4  __attribute__((ext_vector_type(4)));

#define AS1 __attribute__((address_space(1)))
#define AS3 __attribute__((address_space(3)))

__device__ __forceinline__ unsigned short f2bf(float f) {
  union { float f; unsigned int u; } v; v.f = f;
  unsigned int u = v.u;
  u += 0x7fffu + ((u >> 16) & 1u);   // round-to-nearest-even
  return (unsigned short)(u >> 16);
}

__device__ __forceinline__ void async16(const void* g, void* l) {
  __builtin_amdgcn_global_load_lds((const AS1 unsigned int*)g,
                                   (AS3 unsigned int*)l, 16, 0, 0);
}

// ---- kernel 1 (fused): blocks [0,2304) quantize weights; rest do pad/NHWC.
#define TSTR 60
#define QBLKS 2304
__global__ __launch_bounds__(256) void prep(const float* __restrict__ w,
                                            unsigned short* __restrict__ wr,
                                            const float* __restrict__ x,
                                            unsigned short* __restrict__ xp) {
  const int bx = blockIdx.x;
  if (bx < QBLKS) {
    int tid = bx * 256 + threadIdx.x;       // < COUT*KTOT = 589824
    int co  = tid / KTOT;
    int rem = tid - co * KTOT;
    int tap = rem >> 8;          // kh*3+kw
    int ci  = rem & 255;
    int kh  = tap / 3;
    int kw  = tap - kh * 3;
    float v = w[((co * CIN + ci) * 3 + kh) * 3 + kw];
    float q = (fabsf(v) > 0.05f) ? ((v > 0.f) ? 1.f : -1.f) : 0.f;
    wr[tid] = f2bf(q);           // -1/0/+1 exact in bf16
    return;
  }
  const int pbx = bx - QBLKS;            // [0, 1856*4)
  const int nhp = pbx >> 2;              // n*58 + hp
  const int n   = nhp / HP;
  const int hp  = nhp - n * HP;
  const int ci0 = (pbx & 3) << 6;
  const int t   = threadIdx.x;
  const size_t obase = (size_t)nhp * (WP * 256);

  __shared__ __align__(16) float tile[64 * TSTR];
  const bool hborder = (hp == 0) || (hp == HP - 1);

  if (!hborder) {
    const int h = hp - 1;
    #pragma unroll
    for (int it = 0; it < 4; ++it) {
      int linear = it * 256 + t;
      if (linear < 896) {                // 64 ch x 14 float4
        int cil = linear / 14;
        int w4  = linear - cil * 14;
        *(float4*)&tile[cil * TSTR + w4 * 4] =
            *(const float4*)&x[(((size_t)(n * CIN + ci0 + cil)) * HH + h) * WW + w4 * 4];
      }
    }
  }
  __syncthreads();

  #pragma unroll
  for (int it = 0; it < 2; ++it) {               // 58*8 = 464 16B-chunks
    int linear = it * 256 + t;
    if (linear < 464) {
      int wp = linear >> 3;
      int g  = linear & 7;                       // ci group of 8
      unsigned int pk[4] = {0u, 0u, 0u, 0u};
      if (!hborder && wp != 0 && wp != WP - 1) {
        #pragma unroll
        for (int j = 0; j < 4; ++j) {
          int jr = (j + g) & 3;                  // bank-rotation (2-way, free)
          unsigned int lo = f2bf(tile[(g * 8 + 2 * jr) * TSTR + (wp - 1)]);
          unsigned int hi = f2bf(tile[(g * 8 + 2 * jr + 1) * TSTR + (wp - 1)]);
          pk[jr] = lo | (hi << 16);
        }
      }
      uint4 v; v.x = pk[0]; v.y = pk[1]; v.z = pk[2]; v.w = pk[3];
      *(uint4*)(xp + obase + (size_t)wp * 256 + ci0 + g * 8) = v;
    }
  }
}

// ---- kernel 2: implicit GEMM, 256co x 224px, 8 waves (4Mx2N), BK=64/phase.
// ROUND-9: halve the phase count (72 -> 36 barriers).
//   r8 model: per-K32 phase = 1985 cyc; pipe demands are MFMA 1086 (SIMD),
//   LDS reads+writes ~1312 (CU); the ~670 residual is PER-PHASE machinery
//   (8-wave barrier jitter, af-wait, VM drain). Evidence r4->r7->r8: every
//   sync removed helped, every pin hurt. So: one barrier per K=64 tile.
//   - double-buffered 128 KiB: A[2][256][64k], B[2][256][64k] (128-B rows,
//     full-cache-line staging, r4-verified involution swizzle ch^=(row&7)).
//   - dist-1 prefetch: stage(k+1) (8 loads) issued at phase TOP, drained by
//     VM0 at phase END (~2000+ cyc later; HBM worst 900 -> free).
//   - unpinned r7-style body: compiler interleaves 22 ds_reads + 56 MFMAs
//     with counted lgkmcnt. setprio(1) around the MFMA cluster (T5, free).
//   - sched_barrier(0) after each s_barrier: required so next-phase reads
//     can't hoist above the barrier (other waves' staging completes there).
// Hazards: stage(k+1) overwrites tile k-1's buffer -> its reads finished
// before bar(k-1), stage issues after bar(k-1). Reads of tile k+1 happen
// after VM0(k)+bar(k) -> all waves' staging visible. Ledger: only this
// phase's 8 loads ever outstanding at VM0.

#define NOWAIT (void)0
#define VM0 asm volatile("s_waitcnt vmcnt(0)" ::: "memory")

// stage K64-tile kn_ (A 32 KB + B 32 KB) into buffer buf_ (0/1): 8 loads
#define STAGE8(buf_, kn_) do {                                                \
  const int kn__ = (kn_);                                                     \
  const size_t koW_ = (size_t)kn__ << 6;                                      \
  const int tap_ = kn__ >> 2;                                                 \
  const int kh_  = tap_ / 3;                                                  \
  const int kw_  = tap_ - kh_ * 3;                                            \
  const size_t koX_ = (size_t)((kh_ * WP + kw_) * 256 + ((kn__ & 3) << 6));   \
  char* da_ = smem + (buf_) * 32768 + t * 16;                                 \
  char* db_ = smem + 65536 + (buf_) * 32768 + t * 16;                         \
  async16(Wr + koW_ + aSrc0, da_);                                            \
  async16(Wr + koW_ + aSrc1, da_ + 8192);                                     \
  async16(Wr + koW_ + aSrc2, da_ + 16384);                                    \
  async16(Wr + koW_ + aSrc3, da_ + 24576);                                    \
  async16(Xp + koX_ + bSrc[0], db_);                                          \
  async16(Xp + koX_ + bSrc[1], db_ + 8192);                                   \
  async16(Xp + koX_ + bSrc[2], db_ + 16384);                                  \
  async16(Xp + koX_ + bSrc[3], db_ + 24576);                                  \
} while (0)

// one phase = one K=64 tile: stage(k+1) first (VMEM latency hides under the
// whole phase), then 2 x (11 reads + 28 MFMAs) with no internal pins.
#define PHASE(b_, WAITE, ...) do {                                            \
  __VA_ARGS__;                                                                \
  const int ab_ = (b_) * 32768;                                               \
  const int bb_ = 65536 + (b_) * 32768;                                       \
  bf16x8 af0_[4], bf0_[7], af1_[4], bf1_[7];                                  \
  _Pragma("unroll")                                                           \
  for (int mt = 0; mt < 4; ++mt)                                              \
    af0_[mt] = *(const bf16x8*)(smem + ab_ + rdA + mt * 2048 + cX0);          \
  _Pragma("unroll")                                                           \
  for (int nt = 0; nt < 7; ++nt)                                              \
    bf0_[nt] = *(const bf16x8*)(smem + bb_ + rdB + nt * 2048 + cX0);          \
  _Pragma("unroll")                                                           \
  for (int mt = 0; mt < 4; ++mt)                                              \
    af1_[mt] = *(const bf16x8*)(smem + ab_ + rdA + mt * 2048 + cX1);          \
  _Pragma("unroll")                                                           \
  for (int nt = 0; nt < 7; ++nt)                                              \
    bf1_[nt] = *(const bf16x8*)(smem + bb_ + rdB + nt * 2048 + cX1);          \
  __builtin_amdgcn_s_setprio(1);                                              \
  _Pragma("unroll")                                                           \
  for (int mt = 0; mt < 4; ++mt)                                              \
    _Pragma("unroll")                                                         \
    for (int nt = 0; nt < 7; ++nt)                                            \
      acc[mt][nt] = __builtin_amdgcn_mfma_f32_16x16x32_bf16(                  \
          af0_[mt], bf0_[nt], acc[mt][nt], 0, 0, 0);                          \
  _Pragma("unroll")                                                           \
  for (int mt = 0; mt < 4; ++mt)                                              \
    _Pragma("unroll")                                                         \
    for (int nt = 0; nt < 7; ++nt)                                            \
      acc[mt][nt] = __builtin_amdgcn_mfma_f32_16x16x32_bf16(                  \
          af1_[mt], bf1_[nt], acc[mt][nt], 0, 0, 0);                          \
  __builtin_amdgcn_s_setprio(0);                                              \
  WAITE;                                                                      \
  __builtin_amdgcn_s_barrier();                                               \
  __builtin_amdgcn_sched_barrier(0);                                          \
} while (0)

__global__ __launch_bounds__(512, 2) void conv_gemm(
    const unsigned short* __restrict__ Wr,
    const unsigned short* __restrict__ Xp,
    const float* __restrict__ bias,
    float* __restrict__ out) {
  extern __shared__ char smem[];   // 131072 B: A0 A1 @0/32768, B0 B1 @65536/98304

  const int t    = threadIdx.x;
  const int lane = t & 63;
  const int wv   = t >> 6;        // 0..7
  const int wm   = wv >> 1;       // 0..3  co quarter (64)
  const int wn   = wv & 1;        // 0..1  px half (112)
  const int l15  = lane & 15;
  const int quad = lane >> 4;

  // T1: bijective XCD swizzle over 448 = 8 * 56 blocks
  const int bid = blockIdx.x;
  const int pb  = (bid & 7) * 56 + (bid >> 3);
  const int p0  = pb * BN;

  // staging map (128-B rows): thread t -> row t>>3 (+64/sweep), phys chunk
  // t&7, logical chunk = (t&7)^(row&7) [involution, r4-verified; 64%8==0 so
  // all sweeps share the XOR]
  const int srow  = t >> 3;                      // 0..63
  const int sclog = (t & 7) ^ (srow & 7);

  const size_t aSrc0 = (size_t)srow * KTOT + sclog * 8;
  const size_t aSrc1 = aSrc0 + (size_t)64  * KTOT;
  const size_t aSrc2 = aSrc0 + (size_t)128 * KTOT;
  const size_t aSrc3 = aSrc0 + (size_t)192 * KTOT;

  // B rows 0..255 (224 real + 32 pad rows reading harmless workspace bytes)
  size_t bSrc[4];
  #pragma unroll
  for (int s = 0; s < 4; ++s) {
    int p = p0 + s * 64 + srow;
    int n = p / HWSZ; int hw = p - n * HWSZ;
    int h = hw / WW;  int w = hw - h * WW;
    bSrc[s] = ((size_t)((n * HP + h) * WP + w)) * 256 + sclog * 8;
  }

  // read side: row*128 B; k-chunk (kh2*4+quad) ^ (row&7), row&7 == lane&7
  const int rdA = (wm * 64  + l15) * 128;   // + mt*2048
  const int rdB = (wn * 112 + l15) * 128;   // + nt*2048
  const int cX0 = ((quad     ^ (lane & 7)) * 16);
  const int cX1 = (((4+quad) ^ (lane & 7)) * 16);

  f32x4 acc[4][7];
  #pragma unroll
  for (int i = 0; i < 4; ++i)
    #pragma unroll
    for (int j = 0; j < 7; ++j)
      acc[i][j] = (f32x4){0.f, 0.f, 0.f, 0.f};

  // ---- prologue: stage tile 0 into buf 0
  STAGE8(0, 0);
  VM0;
  __builtin_amdgcn_s_barrier();
  __builtin_amdgcn_sched_barrier(0);

  // ---- main: 36 K-tiles of 64; phase k computes buf k&1, stages k+1
  #pragma unroll 1
  for (int it = 0; it < 17; ++it) {
    PHASE(0, VM0, STAGE8(1, 2 * it + 1));
    PHASE(1, VM0, STAGE8(0, 2 * it + 2));
  }
  PHASE(0, VM0, STAGE8(1, 35));    // k=34
  PHASE(1, NOWAIT, NOWAIT);        // k=35

  // ---- epilogue: C/D layout col = lane&15 (pixel), row = quad*4+reg (co)
  float bv[4][4];
  #pragma unroll
  for (int mt = 0; mt < 4; ++mt)
    #pragma unroll
    for (int r = 0; r < 4; ++r)
      bv[mt][r] = bias[wm * 64 + mt * 16 + quad * 4 + r];

  #pragma unroll
  for (int nt = 0; nt < 7; ++nt) {
    const int p  = p0 + wn * 112 + nt * 16 + l15;
    const int np = p / HWSZ;
    const int hw = p - np * HWSZ;
    const size_t obase = (size_t)np * (COUT * HWSZ) + hw;
    #pragma unroll
    for (int mt = 0; mt < 4; ++mt) {
      const int co = wm * 64 + mt * 16 + quad * 4;
      #pragma unroll
      for (int r = 0; r < 4; ++r)
        out[obase + (size_t)(co + r) * HWSZ] = acc[mt][nt][r] + bv[mt][r];
    }
  }
}

extern "C" void kernel_launch(void* const* d_in, const int* in_sizes, int n_in,
                              void* d_out, int out_size, void* d_ws, size_t ws_size,
                              hipStream_t stream) {
  const float* x    = (const float*)d_in[0];
  const float* w    = (const float*)d_in[1];
  const float* bias = (const float*)d_in[2];
  float* out        = (float*)d_out;

  // workspace layout: Xp (padded NHWC bf16) then Wr (reordered ternary bf16)
  unsigned short* xp = (unsigned short*)d_ws;                       // 55,115,776 B
  unsigned short* wr = (unsigned short*)((char*)d_ws + 55115776);   //  1,179,648 B

  prep<<<dim3(QBLKS + BATCH * HP * 4), dim3(256), 0, stream>>>(w, wr, x, xp);

  (void)hipFuncSetAttribute((const void*)conv_gemm,
                            hipFuncAttributeMaxDynamicSharedMemorySize, 131072);
  conv_gemm<<<dim3(NBLK), dim3(512), 131072, stream>>>(wr, xp, bias, out);
}

// Round 10
// 312.944 us; speedup vs baseline: 1.0017x; 1.0017x over previous
//
#include <hip/hip_runtime.h>

#define CIN   256
#define COUT  256
#define HH    56
#define WW    56
#define BATCH 32
#define KTOT  2304           // CIN * 9, ordered (kh,kw,ci)
#define HP    58
#define WP    58
#define NPIX  (BATCH*HH*WW)  // 100352
#define HWSZ  (HH*WW)        // 3136
#define BN    224            // pixel tile -> 448 blocks
#define NBLK  (NPIX/BN)      // 448

typedef __bf16 bf16x8 __attribute__((ext_vector_type(8)));
typedef float  f32x4  __attribute__((ext_vector_type(4)));

#define AS1 __attribute__((address_space(1)))
#define AS3 __attribute__((address_space(3)))

__device__ __forceinline__ unsigned short f2bf(float f) {
  union { float f; unsigned int u; } v; v.f = f;
  unsigned int u = v.u;
  u += 0x7fffu + ((u >> 16) & 1u);   // round-to-nearest-even
  return (unsigned short)(u >> 16);
}

__device__ __forceinline__ void async16(const void* g, void* l) {
  __builtin_amdgcn_global_load_lds((const AS1 unsigned int*)g,
                                   (AS3 unsigned int*)l, 16, 0, 0);
}

// ---- kernel 1 (fused): blocks [0,2304) quantize weights; rest do pad/NHWC.
#define TSTR 60
#define QBLKS 2304
__global__ __launch_bounds__(256) void prep(const float* __restrict__ w,
                                            unsigned short* __restrict__ wr,
                                            const float* __restrict__ x,
                                            unsigned short* __restrict__ xp) {
  const int bx = blockIdx.x;
  if (bx < QBLKS) {
    int tid = bx * 256 + threadIdx.x;       // < COUT*KTOT = 589824
    int co  = tid / KTOT;
    int rem = tid - co * KTOT;
    int tap = rem >> 8;          // kh*3+kw
    int ci  = rem & 255;
    int kh  = tap / 3;
    int kw  = tap - kh * 3;
    float v = w[((co * CIN + ci) * 3 + kh) * 3 + kw];
    float q = (fabsf(v) > 0.05f) ? ((v > 0.f) ? 1.f : -1.f) : 0.f;
    wr[tid] = f2bf(q);           // -1/0/+1 exact in bf16
    return;
  }
  const int pbx = bx - QBLKS;            // [0, 1856*4)
  const int nhp = pbx >> 2;              // n*58 + hp
  const int n   = nhp / HP;
  const int hp  = nhp - n * HP;
  const int ci0 = (pbx & 3) << 6;
  const int t   = threadIdx.x;
  const size_t obase = (size_t)nhp * (WP * 256);

  __shared__ __align__(16) float tile[64 * TSTR];
  const bool hborder = (hp == 0) || (hp == HP - 1);

  if (!hborder) {
    const int h = hp - 1;
    #pragma unroll
    for (int it = 0; it < 4; ++it) {
      int linear = it * 256 + t;
      if (linear < 896) {                // 64 ch x 14 float4
        int cil = linear / 14;
        int w4  = linear - cil * 14;
        *(float4*)&tile[cil * TSTR + w4 * 4] =
            *(const float4*)&x[(((size_t)(n * CIN + ci0 + cil)) * HH + h) * WW + w4 * 4];
      }
    }
  }
  __syncthreads();

  #pragma unroll
  for (int it = 0; it < 2; ++it) {               // 58*8 = 464 16B-chunks
    int linear = it * 256 + t;
    if (linear < 464) {
      int wp = linear >> 3;
      int g  = linear & 7;                       // ci group of 8
      unsigned int pk[4] = {0u, 0u, 0u, 0u};
      if (!hborder && wp != 0 && wp != WP - 1) {
        #pragma unroll
        for (int j = 0; j < 4; ++j) {
          int jr = (j + g) & 3;                  // bank-rotation (2-way, free)
          unsigned int lo = f2bf(tile[(g * 8 + 2 * jr) * TSTR + (wp - 1)]);
          unsigned int hi = f2bf(tile[(g * 8 + 2 * jr + 1) * TSTR + (wp - 1)]);
          pk[jr] = lo | (hi << 16);
        }
      }
      uint4 v; v.x = pk[0]; v.y = pk[1]; v.z = pk[2]; v.w = pk[3];
      *(uint4*)(xp + obase + (size_t)wp * 256 + ci0 + g * 8) = v;
    }
  }
}

// ---- kernel 2: implicit GEMM, 256co x 224px, BK=32, 8 waves (4Mx2N).
// ROUND-10: FULL register double-buffer (A and B).
//   r7-r9 model fit: post-barrier all 8 waves burst reads; first MFMA waits
//   ~480 cyc for operands behind the 88-deep LDS queue, THEN MFMA runs 1086
//   -> phases ~= read-wait + MFMA + sync = 1985. r8 (B-only prefetch) failed
//   because A-reads still gated the MFMA start. Fix: phase k's MFMAs run
//   ENTIRELY from registers loaded during phase k-1; phase k's ds_reads
//   (tile k+1, both A and B) have no consumer this phase -> LDS pipe and
//   MFMA pipe overlap fully; compiler's counted lgkm wait lands next-phase
//   (a full ~1400 cyc of slack -> free).
//   - NB=4 LDS buffers (4 x 32 KB = 128 KiB), BK=32, 64-B rows, r3-verified
//     0-conflict swizzle chunk^=(row>>1)&3 (inverse on global source).
//   - stage(k+3) at phase TOP; VM4 at phase END: outstanding = stage(k+3)
//     (this phase) + stage(k+2) (prev) = 8 -> drains stage(k+2), exactly
//     what phase k+1's reads need. stage(k+3) rides >=1 more full phase.
//   - overwrite hazard: buf[(k+3)%4] holds tile k-1, whose reads completed
//     before bar(k-1) (lgkm wait precedes phase k-1's MFMAs); stage issues
//     after bar(k-1). Tail: VM0@69 drains stage(71); DORD=0 at k=71.
//   - registers: acc 112 + 2x(16 A + 28 B) = 200 + addressing ~35 < 256:
//     keeps 2 waves/SIMD (fail signal: VGPR>150 or scratch).

#define NOWAIT (void)0
#define VM4 asm volatile("s_waitcnt vmcnt(4)" ::: "memory")
#define VM0 asm volatile("s_waitcnt vmcnt(0)" ::: "memory")

// stage K32-tile kn_ (A 16 KB + B 16 KB) into buffer buf_ (0..3): 4 loads
#define STAGE4(buf_, kn_) do {                                                \
  const int kn__ = (kn_);                                                     \
  const size_t koW_ = (size_t)kn__ << 5;                                      \
  const int tap_ = kn__ >> 3;                                                  \
  const int kh_  = tap_ / 3;                                                  \
  const int kw_  = tap_ - kh_ * 3;                                            \
  const size_t koX_ = (size_t)((kh_ * WP + kw_) * 256 + ((kn__ & 7) << 5));   \
  char* da_ = smem + (buf_) * 32768 + t * 16;                                 \
  char* db_ = smem + (buf_) * 32768 + 16384 + t * 16;                         \
  async16(Wr + koW_ + aSrc0, da_);                                            \
  async16(Wr + koW_ + aSrc1, da_ + 8192);                                     \
  async16(Xp + koX_ + bSrc0, db_);                                            \
  async16(Xp + koX_ + bSrc1, db_ + 8192);                                     \
} while (0)

// phase k: stage(k+3) -> read af/bf(k+1) from bufR into nxt sets (no consumer
// this phase) -> 28 MFMAs purely from cur sets -> VM4 -> barrier.
#define PHASE(bR_, cA_, cB_, nA_, nB_, DORD_, WAITE, ...) do {                \
  __VA_ARGS__;                                                                \
  if (DORD_) {                                                                \
    _Pragma("unroll")                                                         \
    for (int mt = 0; mt < 4; ++mt)                                            \
      nA_[mt] = *(const bf16x8*)(smem + (bR_) * 32768 + rdA + mt * 1024);     \
    _Pragma("unroll")                                                         \
    for (int nt = 0; nt < 7; ++nt)                                            \
      nB_[nt] = *(const bf16x8*)(smem + (bR_) * 32768 + 16384 + rdB + nt * 1024);\
  }                                                                           \
  __builtin_amdgcn_s_setprio(1);                                              \
  _Pragma("unroll")                                                           \
  for (int mt = 0; mt < 4; ++mt)                                              \
    _Pragma("unroll")                                                         \
    for (int nt = 0; nt < 7; ++nt)                                            \
      acc[mt][nt] = __builtin_amdgcn_mfma_f32_16x16x32_bf16(                  \
          cA_[mt], cB_[nt], acc[mt][nt], 0, 0, 0);                            \
  __builtin_amdgcn_s_setprio(0);                                              \
  WAITE;                                                                      \
  __builtin_amdgcn_s_barrier();                                               \
  __builtin_amdgcn_sched_barrier(0);                                          \
} while (0)

__global__ __launch_bounds__(512, 2) void conv_gemm(
    const unsigned short* __restrict__ Wr,
    const unsigned short* __restrict__ Xp,
    const float* __restrict__ bias,
    float* __restrict__ out) {
  extern __shared__ char smem[];   // 131072 B: buf{0..3} of (A 16K | B 16K)

  const int t    = threadIdx.x;
  const int lane = t & 63;
  const int wv   = t >> 6;        // 0..7
  const int wm   = wv >> 1;       // 0..3  co quarter (64)
  const int wn   = wv & 1;        // 0..1  px half (112)
  const int l15  = lane & 15;
  const int quad = lane >> 4;

  // T1: bijective XCD swizzle over 448 = 8 * 56 blocks
  const int bid = blockIdx.x;
  const int pb  = (bid & 7) * 56 + (bid >> 3);
  const int p0  = pb * BN;

  // staging map: thread t -> rows (t>>2, +128), phys chunk t&3,
  // logical chunk = (t&3) ^ ((row>>1)&3)  [T2 inverse on global source]
  const int srow = t >> 2;                       // 0..127
  const int schk = (t & 3) ^ ((srow >> 1) & 3);

  const size_t aSrc0 = (size_t)srow * KTOT + schk * 8;
  const size_t aSrc1 = aSrc0 + (size_t)128 * KTOT;

  // B rows 0..255 (224 real + 32 pad rows reading harmless workspace bytes)
  const int pA = p0 + srow;
  const int pB = pA + 128;
  const int nA = pA / HWSZ;  const int hwA = pA - nA * HWSZ;
  const int hA = hwA / WW;   const int wA  = hwA - hA * WW;
  const int nB = pB / HWSZ;  const int hwB = pB - nB * HWSZ;
  const int hB = hwB / WW;   const int wB  = hwB - hB * WW;
  const size_t bSrc0 = ((size_t)((nA * HP + hA) * WP + wA)) * 256 + schk * 8;
  const size_t bSrc1 = ((size_t)((nB * HP + hB) * WP + wB)) * 256 + schk * 8;

  // read side: row*64 B; logical k-quad 'quad' -> phys chunk quad^((row>>1)&3)
  const int rchk = (quad ^ ((l15 >> 1) & 3)) * 16;
  const int rdA  = (wm * 64  + l15) * 64 + rchk;   // + mt*1024
  const int rdB  = (wn * 112 + l15) * 64 + rchk;   // + nt*1024

  f32x4 acc[4][7];
  #pragma unroll
  for (int i = 0; i < 4; ++i)
    #pragma unroll
    for (int j = 0; j < 7; ++j)
      acc[i][j] = (f32x4){0.f, 0.f, 0.f, 0.f};

  bf16x8 afA[4], afB[4], bfA[7], bfB[7];   // register double-buffer (A and B)

  // ---- prologue: stage tiles 0,1,2 into bufs 0,1,2; VM4 drains stages 0,1
  // (leaves stage 2 in flight); pre-read tile 0 into set A.
  STAGE4(0, 0);
  STAGE4(1, 1);
  STAGE4(2, 2);
  VM4;
  __builtin_amdgcn_s_barrier();
  __builtin_amdgcn_sched_barrier(0);
  #pragma unroll
  for (int mt = 0; mt < 4; ++mt)
    afA[mt] = *(const bf16x8*)(smem + rdA + mt * 1024);
  #pragma unroll
  for (int nt = 0; nt < 7; ++nt)
    bfA[nt] = *(const bf16x8*)(smem + 16384 + rdB + nt * 1024);

  // ---- main: k = 0..67 (17 x 4); bufR = (k+1)%4, stage buf (k+3)%4,
  // reg sets alternate by parity (k even: cur=A).
  #pragma unroll 1
  for (int it = 0; it < 17; ++it) {
    const int k0 = 4 * it;
    PHASE(1, afA, bfA, afB, bfB, 1, VM4, STAGE4(3, k0 + 3));
    PHASE(2, afB, bfB, afA, bfA, 1, VM4, STAGE4(0, k0 + 4));
    PHASE(3, afA, bfA, afB, bfB, 1, VM4, STAGE4(1, k0 + 5));
    PHASE(0, afB, bfB, afA, bfA, 1, VM4, STAGE4(2, k0 + 6));
  }
  // ---- peeled tail: k = 68..71
  PHASE(1, afA, bfA, afB, bfB, 1, VM4, STAGE4(3, 71));  // k=68: stage last
  PHASE(2, afB, bfB, afA, bfA, 1, VM0, NOWAIT);         // k=69: drain 71
  PHASE(3, afA, bfA, afB, bfB, 1, NOWAIT, NOWAIT);      // k=70: read tile 71
  PHASE(0, afB, bfB, afA, bfA, 0, NOWAIT, NOWAIT);      // k=71: no reads

  // ---- epilogue: C/D layout col = lane&15 (pixel), row = quad*4+reg (co)
  float bv[4][4];
  #pragma unroll
  for (int mt = 0; mt < 4; ++mt)
    #pragma unroll
    for (int r = 0; r < 4; ++r)
      bv[mt][r] = bias[wm * 64 + mt * 16 + quad * 4 + r];

  #pragma unroll
  for (int nt = 0; nt < 7; ++nt) {
    const int p  = p0 + wn * 112 + nt * 16 + l15;
    const int np = p / HWSZ;
    const int hw = p - np * HWSZ;
    const size_t obase = (size_t)np * (COUT * HWSZ) + hw;
    #pragma unroll
    for (int mt = 0; mt < 4; ++mt) {
      const int co = wm * 64 + mt * 16 + quad * 4;
      #pragma unroll
      for (int r = 0; r < 4; ++r)
        out[obase + (size_t)(co + r) * HWSZ] = acc[mt][nt][r] + bv[mt][r];
    }
  }
}

extern "C" void kernel_launch(void* const* d_in, const int* in_sizes, int n_in,
                              void* d_out, int out_size, void* d_ws, size_t ws_size,
                              hipStream_t stream) {
  const float* x    = (const float*)d_in[0];
  const float* w    = (const float*)d_in[1];
  const float* bias = (const float*)d_in[2];
  float* out        = (float*)d_out;

  // workspace layout: Xp (padded NHWC bf16) then Wr (reordered ternary bf16)
  unsigned short* xp = (unsigned short*)d_ws;                       // 55,115,776 B
  unsigned short* wr = (unsigned short*)((char*)d_ws + 55115776);   //  1,179,648 B

  prep<<<dim3(QBLKS + BATCH * HP * 4), dim3(256), 0, stream>>>(w, wr, x, xp);

  (void)hipFuncSetAttribute((const void*)conv_gemm,
                            hipFuncAttributeMaxDynamicSharedMemorySize, 131072);
  conv_gemm<<<dim3(NBLK), dim3(512), 131072, stream>>>(wr, xp, bias, out);
}

// Round 12
// 306.087 us; speedup vs baseline: 1.0242x; 1.0224x over previous
//
#include <hip/hip_runtime.h>

#define CIN   256
#define COUT  256
#define HH    56
#define WW    56
#define BATCH 32
#define KTOT  2304           // CIN * 9, ordered (kh,kw,ci)
#define HP    58
#define WP    58
#define NPIX  (BATCH*HH*WW)  // 100352
#define HWSZ  (HH*WW)        // 3136
#define BN    224            // pixel tile -> 448 blocks
#define NBLK  (NPIX/BN)      // 448

typedef __bf16 bf16x8 __attribute__((ext_vector_type(8)));
typedef float  f32x4  __attribute__((ext_vector_type(4)));

#define AS1 __attribute__((address_space(1)))
#define AS3 __attribute__((address_space(3)))

__device__ __forceinline__ unsigned short f2bf(float f) {
  union { float f; unsigned int u; } v; v.f = f;
  unsigned int u = v.u;
  u += 0x7fffu + ((u >> 16) & 1u);   // round-to-nearest-even
  return (unsigned short)(u >> 16);
}

__device__ __forceinline__ void async16(const void* g, void* l) {
  __builtin_amdgcn_global_load_lds((const AS1 unsigned int*)g,
                                   (AS3 unsigned int*)l, 16, 0, 0);
}

// ---- kernel 1 (fused prep):
//  blocks [0,128): quantize weights, 2 co per block.
//    read coalesced (lane ci covers w[co][ci][0..8], dense 36B/lane),
//    LDS-transpose to [tap][ci], write wr coalesced as uint4.
//  blocks [128, 128+1856): pad, one block per (n, hp), ALL 256 ci.
//    Load: f32x4 from x, convert to bf16 AT LOAD, store to transposed tile
//      tileT[w][ (ci + 8w) & 255 ] (u16). Rotation spreads the store banks
//      (2-way, free) AND makes the pack read 8 consecutive u16.
//    Pack: ONE ds_read_b128 (16B aligned, <=4-way banks) + ONE dwordx4
//      store per output chunk — was 8 scalar LDS reads w/ inherent 8-way
//      conflict (8 x rowstride = 0 mod 32 for any stride%4==0).
//    bf16 tile = 28 KB -> 4 blocks/CU resident (was 2) for latency hiding.
__global__ __launch_bounds__(512) void prep(const float* __restrict__ w,
                                            unsigned short* __restrict__ wr,
                                            const float* __restrict__ x,
                                            unsigned short* __restrict__ xp) {
  __shared__ __align__(16) unsigned short sh[56 * 256];   // 28672 B
  const int bx = blockIdx.x;
  const int t  = threadIdx.x;

  if (bx < 128) {
    // ---- quant: 2 co per block
    const int ci  = t & 255;
    const int sub = t >> 8;
    const int co  = bx * 2 + sub;
    const float* ws = w + (size_t)co * 2304 + ci * 9;
    unsigned short* qs = sh + sub * 2304;
    #pragma unroll
    for (int j = 0; j < 9; ++j) {
      float v = ws[j];
      float q = (fabsf(v) > 0.05f) ? ((v > 0.f) ? 1.f : -1.f) : 0.f;
      qs[j * 256 + ci] = f2bf(q);          // [tap][ci]
    }
    __syncthreads();
    // 2 co x 2304 u16 = 576 uint4, coalesced
    uint4* dst = (uint4*)(wr + (size_t)bx * 2 * 2304);
    const uint4* src = (const uint4*)sh;
    dst[t] = src[t];
    if (t < 64) dst[512 + t] = src[512 + t];
    return;
  }

  // ---- pad: one (n, hp) row, all 256 channels
  const int pbx = bx - 128;
  const int n   = pbx / HP;
  const int hp  = pbx - n * HP;
  const size_t obase = (size_t)(n * HP + hp) * (WP * 256);
  const bool hb = (hp == 0) || (hp == HP - 1);

  if (!hb) {
    const int h = hp - 1;
    #pragma unroll
    for (int it = 0; it < 7; ++it) {           // 256 ci x 14 f32x4 = 3584
      int lin = it * 512 + t;
      int ci  = lin / 14;
      int w4  = lin - ci * 14;
      float4 v = *(const float4*)&x[((size_t)(n * CIN + ci) * HH + h) * WW + w4 * 4];
      #pragma unroll
      for (int k = 0; k < 4; ++k) {
        int wdx = w4 * 4 + k;
        sh[wdx * 256 + ((ci + 8 * wdx) & 255)] = f2bf(((const float*)&v)[k]);
      }
    }
  }
  __syncthreads();

  #pragma unroll
  for (int it = 0; it < 4; ++it) {             // 58 wp x 32 chunks = 1856
    int lin = it * 512 + t;
    if (lin < 1856) {
      int wp = lin >> 5;
      int g2 = lin & 31;
      uint4 v = {0u, 0u, 0u, 0u};
      if (!hb && wp != 0 && wp != WP - 1) {
        int wdx = wp - 1;
        v = *(const uint4*)&sh[wdx * 256 + ((g2 * 8 + 8 * wdx) & 255)];
      }
      *(uint4*)(xp + obase + (size_t)wp * 256 + g2 * 8) = v;
    }
  }
}

// ---- kernel 2: implicit GEMM, 256co x 224px, BK=32, 8 waves (4Mx2N).
// EXACT r8 kernel (best measured: 119.0 us) — quad-buffered LDS, dist-3
// staging, counted VM4, B-fragment register double-buffer, r3-verified
// 0-conflict swizzle, bijective XCD swizzle. Untouched.

#define NOWAIT (void)0
#define VM4 asm volatile("s_waitcnt vmcnt(4)" ::: "memory")
#define VM0 asm volatile("s_waitcnt vmcnt(0)" ::: "memory")

#define STAGE4(buf_, kn_) do {                                                \
  const int kn__ = (kn_);                                                     \
  const size_t koW_ = (size_t)kn__ << 5;                                      \
  const int tap_ = kn__ >> 3;                                                 \
  const int kh_  = tap_ / 3;                                                  \
  const int kw_  = tap_ - kh_ * 3;                                            \
  const size_t koX_ = (size_t)((kh_ * WP + kw_) * 256 + ((kn__ & 7) << 5));   \
  char* da_ = smem + (buf_) * 32768 + t * 16;                                 \
  char* db_ = smem + (buf_) * 32768 + 16384 + t * 16;                         \
  async16(Wr + koW_ + aSrc0, da_);                                            \
  async16(Wr + koW_ + aSrc1, da_ + 8192);                                     \
  async16(Xp + koX_ + bSrc0, db_);                                            \
  async16(Xp + koX_ + bSrc1, db_ + 8192);                                     \
} while (0)

#define PHASE(bc_, bn_, cur_, nxt_, DOBF_, WAITE, ...) do {                   \
  __VA_ARGS__;                                                                \
  bf16x8 af_[4];                                                              \
  _Pragma("unroll")                                                           \
  for (int mt = 0; mt < 4; ++mt)                                              \
    af_[mt] = *(const bf16x8*)(smem + (bc_) * 32768 + rdA + mt * 1024);       \
  if (DOBF_) {                                                                \
    _Pragma("unroll")                                                         \
    for (int nt = 0; nt < 7; ++nt)                                            \
      nxt_[nt] = *(const bf16x8*)(smem + (bn_) * 32768 + 16384 + rdB + nt * 1024);\
  }                                                                           \
  _Pragma("unroll")                                                           \
  for (int mt = 0; mt < 4; ++mt)                                              \
    _Pragma("unroll")                                                         \
    for (int nt = 0; nt < 7; ++nt)                                            \
      acc[mt][nt] = __builtin_amdgcn_mfma_f32_16x16x32_bf16(                  \
          af_[mt], cur_[nt], acc[mt][nt], 0, 0, 0);                           \
  WAITE;                                                                      \
  __builtin_amdgcn_s_barrier();                                               \
  __builtin_amdgcn_sched_barrier(0);                                          \
} while (0)

__global__ __launch_bounds__(512, 2) void conv_gemm(
    const unsigned short* __restrict__ Wr,
    const unsigned short* __restrict__ Xp,
    const float* __restrict__ bias,
    float* __restrict__ out) {
  extern __shared__ char smem[];   // 131072 B: buf{0..3} of (A 16K | B 16K)

  const int t    = threadIdx.x;
  const int lane = t & 63;
  const int wv   = t >> 6;        // 0..7
  const int wm   = wv >> 1;       // 0..3  co quarter (64)
  const int wn   = wv & 1;        // 0..1  px half (112)
  const int l15  = lane & 15;
  const int quad = lane >> 4;

  // T1: bijective XCD swizzle over 448 = 8 * 56 blocks
  const int bid = blockIdx.x;
  const int pb  = (bid & 7) * 56 + (bid >> 3);
  const int p0  = pb * BN;

  // staging map: thread t -> rows (t>>2, +128), phys chunk t&3,
  // logical chunk = (t&3) ^ ((row>>1)&3)  [T2 inverse on global source]
  const int srow = t >> 2;                       // 0..127
  const int schk = (t & 3) ^ ((srow >> 1) & 3);

  const size_t aSrc0 = (size_t)srow * KTOT + schk * 8;
  const size_t aSrc1 = aSrc0 + (size_t)128 * KTOT;

  // B rows 0..255 (224 real + 32 pad rows reading harmless workspace bytes)
  const int pA = p0 + srow;
  const int pB = pA + 128;
  const int nA = pA / HWSZ;  const int hwA = pA - nA * HWSZ;
  const int hA = hwA / WW;   const int wA  = hwA - hA * WW;
  const int nB = pB / HWSZ;  const int hwB = pB - nB * HWSZ;
  const int hB = hwB / WW;   const int wB  = hwB - hB * WW;
  const size_t bSrc0 = ((size_t)((nA * HP + hA) * WP + wA)) * 256 + schk * 8;
  const size_t bSrc1 = ((size_t)((nB * HP + hB) * WP + wB)) * 256 + schk * 8;

  // read side: row*64 B; logical k-quad 'quad' -> phys chunk quad^((row>>1)&3)
  const int rchk = (quad ^ ((l15 >> 1) & 3)) * 16;
  const int rdA  = (wm * 64  + l15) * 64 + rchk;   // + mt*1024
  const int rdB  = (wn * 112 + l15) * 64 + rchk;   // + nt*1024

  f32x4 acc[4][7];
  #pragma unroll
  for (int i = 0; i < 4; ++i)
    #pragma unroll
    for (int j = 0; j < 7; ++j)
      acc[i][j] = (f32x4){0.f, 0.f, 0.f, 0.f};

  bf16x8 bfA[7], bfB[7];           // register-double-buffered B fragments

  // ---- prologue: stage tiles 0,1,2 into bufs 0,1,2; drain 0 AND 1 (VM4
  // with 12 outstanding -> 4); pre-read bf(0) into set A.
  STAGE4(0, 0);
  STAGE4(1, 1);
  STAGE4(2, 2);
  VM4;
  __builtin_amdgcn_s_barrier();
  __builtin_amdgcn_sched_barrier(0);
  #pragma unroll
  for (int nt = 0; nt < 7; ++nt)
    bfA[nt] = *(const bf16x8*)(smem + 16384 + rdB + nt * 1024);

  // ---- main: k = 0..67 (17 x 4 phases); buffers cycle %4, bf sets by parity
  #pragma unroll 1
  for (int it = 0; it < 17; ++it) {
    const int k0 = 4 * it;
    PHASE(0, 1, bfA, bfB, 1, VM4, STAGE4(3, k0 + 3));
    PHASE(1, 2, bfB, bfA, 1, VM4, STAGE4(0, k0 + 4));
    PHASE(2, 3, bfA, bfB, 1, VM4, STAGE4(1, k0 + 5));
    PHASE(3, 0, bfB, bfA, 1, VM4, STAGE4(2, k0 + 6));
  }
  // ---- peeled drain: k = 68..71
  PHASE(0, 1, bfA, bfB, 1, VM4, STAGE4(3, 71));   // k=68: stage last tile
  PHASE(1, 2, bfB, bfA, 1, VM0, NOWAIT);          // k=69: drain tile 71
  PHASE(2, 3, bfA, bfB, 1, NOWAIT, NOWAIT);       // k=70: bf(71) from buf 3
  PHASE(3, 0, bfB, bfA, 0, NOWAIT, NOWAIT);       // k=71: no bf read

  // ---- epilogue: C/D layout col = lane&15 (pixel), row = quad*4+reg (co)
  float bv[4][4];
  #pragma unroll
  for (int mt = 0; mt < 4; ++mt)
    #pragma unroll
    for (int r = 0; r < 4; ++r)
      bv[mt][r] = bias[wm * 64 + mt * 16 + quad * 4 + r];

  #pragma unroll
  for (int nt = 0; nt < 7; ++nt) {
    const int p  = p0 + wn * 112 + nt * 16 + l15;
    const int np = p / HWSZ;
    const int hw = p - np * HWSZ;
    const size_t obase = (size_t)np * (COUT * HWSZ) + hw;
    #pragma unroll
    for (int mt = 0; mt < 4; ++mt) {
      const int co = wm * 64 + mt * 16 + quad * 4;
      #pragma unroll
      for (int r = 0; r < 4; ++r)
        out[obase + (size_t)(co + r) * HWSZ] = acc[mt][nt][r] + bv[mt][r];
    }
  }
}

extern "C" void kernel_launch(void* const* d_in, const int* in_sizes, int n_in,
                              void* d_out, int out_size, void* d_ws, size_t ws_size,
                              hipStream_t stream) {
  const float* x    = (const float*)d_in[0];
  const float* w    = (const float*)d_in[1];
  const float* bias = (const float*)d_in[2];
  float* out        = (float*)d_out;

  // workspace layout: Xp (padded NHWC bf16) then Wr (reordered ternary bf16)
  unsigned short* xp = (unsigned short*)d_ws;                       // 55,115,776 B
  unsigned short* wr = (unsigned short*)((char*)d_ws + 55115776);   //  1,179,648 B

  // 128 quant blocks (2 co each) + 1856 pad blocks (one (n,hp) each)
  prep<<<dim3(128 + BATCH * HP), dim3(512), 0, stream>>>(w, wr, x, xp);

  (void)hipFuncSetAttribute((const void*)conv_gemm,
                            hipFuncAttributeMaxDynamicSharedMemorySize, 131072);
  conv_gemm<<<dim3(NBLK), dim3(512), 131072, stream>>>(wr, xp, bias, out);
}